// Round 6
// baseline (548.588 us; speedup 1.0000x reference)
//
#include <hip/hip_runtime.h>

// LoraLinear NF4: out = x @ W_eff^T, W_eff = NF4[codes]*absmax + 2*(lora_B @ lora_A)
// M=8192 (4*2048), N=4096, K=4096. f16 MFMA GEMM, 256^2 tile, BK=64, 8 waves.
// R8: R3/R6/R7 all hit 48% MfmaUtil regardless of barrier structure ->
// bottleneck is WAR on fragment regs (in-order issue: reads can't start until
// the consuming MFMA cluster finished issuing) serializing LDS port with MFMA
// pipe. Fix:
//  (1) 32x32x16 MFMA: per-kstep frag set = 24 VGPR (vs 48), pipe 13% faster.
//      A/B layout: row=lane%32, k = 8*(lane>>5)+[0..8) contiguous (16B/lane).
//      C/D: col=lane&31, row=(reg&3)+8*(reg>>2)+4*(lane>>5) [m74/m101].
//  (2) Double-buffered fragment sets (afA/bfA, afB/bfB): reads for kstep k+1
//      issue BEFORE MFMA cluster k (no WAR) -> LDS drains under the 541-cyc
//      pipe occupancy; LG(6) gates are then ~free.
// Per tile: RD(k0) | stage all 4 regions of tile T+1 into BUF^1 | RD(k1) |
//   [LG(6) MFMA(k0)] RD(k2) [LG(6) MFMA(k1)] RD(k3) [LG(6) MFMA(k2)]
//   [LG(0) MFMA(k3)] VMC(0) BAR    -- single barrier per tile (R7 scheme).
// Cross-wave safety (unchanged from R7, which passed): BUF^1 fully dead after
// tile T's start barrier (stages overwrite-safe); VMC(0)+BAR publishes T+1;
// compiler tracks all ds_read->MFMA deps (LG/SB0 only shape the schedule);
// gl16->ds_read ordering is the VMC(0)+BAR (compiler can't see it).
// T1 XCD swizzle, T2 LDS XOR chunk swizzle (both sides), T5 setprio kept.

typedef _Float16 half8 __attribute__((ext_vector_type(8)));
typedef float f32x16 __attribute__((ext_vector_type(16)));

#define M_DIM 8192
#define N_DIM 4096
#define K_DIM 4096
#define NT (K_DIM / 64)

__constant__ float NF4C[16] = {
    -1.0f, -0.6961928009986877f, -0.5250730514526367f, -0.39491748809814453f,
    -0.28444138169288635f, -0.18477343022823334f, -0.09105003625154495f, 0.0f,
    0.07958029955625534f, 0.16093020141124725f, 0.24611230194568634f, 0.33791524171829224f,
    0.44070982933044434f, 0.5626170039176941f, 0.7229568362236023f, 1.0f};

__device__ __forceinline__ void gl16(void* lds_p, const void* g) {
  __builtin_amdgcn_global_load_lds(
      (const __attribute__((address_space(1))) void*)g,
      (__attribute__((address_space(3))) void*)lds_p, 16, 0, 0);
}

// ---------------- prep_x: fp32 -> f16 cast of x ----------------
__global__ __launch_bounds__(256) void prep_x(const float4* __restrict__ x,
                                              half8* __restrict__ xh) {
  size_t i = (size_t)blockIdx.x * 256 + threadIdx.x;
  float4 a = x[2 * i];
  float4 b = x[2 * i + 1];
  half8 h;
  h[0] = (_Float16)a.x; h[1] = (_Float16)a.y; h[2] = (_Float16)a.z; h[3] = (_Float16)a.w;
  h[4] = (_Float16)b.x; h[5] = (_Float16)b.y; h[6] = (_Float16)b.z; h[7] = (_Float16)b.w;
  xh[i] = h;
}

// ---------------- prep_w: dequant NF4 + fold 2*B@A, write f16 ----------------
#define PWP 132
__global__ __launch_bounds__(256) void prep_w(const float* __restrict__ lora_A,
                                              const float* __restrict__ lora_B,
                                              const float* __restrict__ absmax,
                                              const int* __restrict__ codes,
                                              _Float16* __restrict__ Wc) {
  __shared__ float At[64 * PWP];
  __shared__ float Bt[64 * PWP];
  __shared__ float nf4s[16];
  const int tid = threadIdx.x;
  const int bxi = blockIdx.x & 31;
  const int byo = blockIdx.x >> 5;
  const int i0 = bxi * 128;
  const int o0 = byo * 128;
  if (tid < 16) nf4s[tid] = NF4C[tid];
  for (int idx = tid; idx < 8192; idx += 256) {
    int r = idx >> 7, ii = idx & 127;
    At[r * PWP + ii] = lora_A[(size_t)r * 4096 + i0 + ii];
  }
  for (int idx = tid; idx < 8192; idx += 256) {
    int oo = idx >> 6, r = idx & 63;
    Bt[r * PWP + oo] = lora_B[(size_t)(o0 + oo) * 64 + r];
  }
  __syncthreads();
  const int tx = tid & 15;
  const int ty = tid >> 4;
  float accw[8][8];
#pragma unroll
  for (int i = 0; i < 8; ++i)
#pragma unroll
    for (int j = 0; j < 8; ++j) accw[i][j] = 0.0f;
  for (int r = 0; r < 64; ++r) {
    float4 a0 = *(const float4*)&At[r * PWP + tx * 8];
    float4 a1 = *(const float4*)&At[r * PWP + tx * 8 + 4];
    float4 b0 = *(const float4*)&Bt[r * PWP + ty * 8];
    float4 b1 = *(const float4*)&Bt[r * PWP + ty * 8 + 4];
    float av[8] = {a0.x, a0.y, a0.z, a0.w, a1.x, a1.y, a1.z, a1.w};
    float bv[8] = {b0.x, b0.y, b0.z, b0.w, b1.x, b1.y, b1.z, b1.w};
#pragma unroll
    for (int i = 0; i < 8; ++i)
#pragma unroll
      for (int j = 0; j < 8; ++j) accw[i][j] += bv[i] * av[j];
  }
#pragma unroll
  for (int i = 0; i < 8; ++i) {
    const int o_g = o0 + ty * 8 + i;
    const int* crow = codes + (size_t)o_g * 4096 + i0 + tx * 8;
    int4 c0 = *(const int4*)crow;
    int4 c1 = *(const int4*)(crow + 4);
    const float am = absmax[o_g * 64 + (i0 >> 6) + (tx >> 3)];
    half8 h;
    h[0] = (_Float16)(nf4s[c0.x] * am + 2.0f * accw[i][0]);
    h[1] = (_Float16)(nf4s[c0.y] * am + 2.0f * accw[i][1]);
    h[2] = (_Float16)(nf4s[c0.z] * am + 2.0f * accw[i][2]);
    h[3] = (_Float16)(nf4s[c0.w] * am + 2.0f * accw[i][3]);
    h[4] = (_Float16)(nf4s[c1.x] * am + 2.0f * accw[i][4]);
    h[5] = (_Float16)(nf4s[c1.y] * am + 2.0f * accw[i][5]);
    h[6] = (_Float16)(nf4s[c1.z] * am + 2.0f * accw[i][6]);
    h[7] = (_Float16)(nf4s[c1.w] * am + 2.0f * accw[i][7]);
    *(half8*)(Wc + (size_t)o_g * 4096 + i0 + tx * 8) = h;
  }
}

// ---------------- gemm: C[M,N] = Xh[M,K] * Wc[N,K]^T ----------------
// LDS f16 offsets: region(buf,isB,half) = buf*32768 + isB*16384 + half*8192.
// Within region: row r (0..127), 16B chunk c (0..7); physical c = logical ^ (r&7).

#define BAR __builtin_amdgcn_s_barrier()
#define PRIO1 __builtin_amdgcn_s_setprio(1)
#define PRIO0 __builtin_amdgcn_s_setprio(0)

#define VMC_(N) asm volatile("s_waitcnt vmcnt(" #N ")" ::: "memory")
#define VMC(N) VMC_(N)
#define LG_(N)                                              \
  do {                                                      \
    asm volatile("s_waitcnt lgkmcnt(" #N ")" ::: "memory"); \
    __builtin_amdgcn_sched_barrier(0);                      \
  } while (0)
#define LG(N) LG_(N)

__global__ __launch_bounds__(512, 2) void gemm(const _Float16* __restrict__ Xh,
                                               const _Float16* __restrict__ Wc,
                                               float* __restrict__ out) {
  __shared__ _Float16 lds[65536];  // 128 KiB
  const int tid = threadIdx.x;
  const int lane = tid & 63;
  const int w = tid >> 6;  // wave 0..7; 2M x 4N

  // T1: bijective XCD swizzle (512 wgs, 8 XCDs, 64 per XCD)
  const int swz = (blockIdx.x & 7) * 64 + (blockIdx.x >> 3);
  const int by = swz >> 4;  // 0..31 (M/256)
  const int bx = swz & 15;  // 0..15 (N/256)

  // fragment addressing (32x32x16): row = lane&31, k-half = lane>>5
  const int l31 = lane & 31;
  const int kh = lane >> 5;
  const int rb = l31 & 7;           // swizzle row bits (frag rows == l31 mod 8)
  const int aro = l31 * 64;         // f16 offset of lane's row within region
  // swizzled 16B-chunk offsets (f16 units) for ksteps 0..3
  const int ck0 = ((0 | kh) ^ rb) * 8;
  const int ck1 = ((2 | kh) ^ rb) * 8;
  const int ck2 = ((4 | kh) ^ rb) * 8;
  const int ck3 = ((6 | kh) ^ rb) * 8;
  const int ha = w >> 2;            // wave's A half-region
  const int hboff = ((w & 3) >> 1) * 8192 + (w & 1) * 4096;  // B 64-row block

  // staging source (T2 inverse swizzle on global source; LDS dest linear)
  const int r0 = tid >> 3;
  const int lc = (tid & 7) ^ (r0 & 7);
  const _Float16* gAbase = Xh + (size_t)(by * 256 + r0) * K_DIM + lc * 8;
  const _Float16* gBbase = Wc + (size_t)(bx * 256 + r0) * K_DIM + lc * 8;

#define STAGE_A(H, BUF, T)                                                \
  do {                                                                    \
    _Float16* d_ = lds + (BUF) * 32768 + (H) * 8192 + w * 512;            \
    const _Float16* s_ = gAbase + (size_t)((H) * 128) * K_DIM + (T) * 64; \
    gl16(d_, s_);                                                         \
    gl16(d_ + 4096, s_ + (size_t)64 * K_DIM);                             \
  } while (0)
#define STAGE_B(H, BUF, T)                                                \
  do {                                                                    \
    _Float16* d_ = lds + (BUF) * 32768 + 16384 + (H) * 8192 + w * 512;    \
    const _Float16* s_ = gBbase + (size_t)((H) * 128) * K_DIM + (T) * 64; \
    gl16(d_, s_);                                                         \
    gl16(d_ + 4096, s_ + (size_t)64 * K_DIM);                             \
  } while (0)

  f32x16 acc[4][2];
#pragma unroll
  for (int m = 0; m < 4; ++m)
#pragma unroll
    for (int n = 0; n < 2; ++n)
#pragma unroll
      for (int i = 0; i < 16; ++i) acc[m][n][i] = 0.0f;

  half8 afA[4], bfA[2];  // fragment set A
  half8 afB[4], bfB[2];  // fragment set B

  // 6 ds_read_b128: 4 A-frags (mt*32 rows apart) + 2 B-frags (nt*32 apart)
#define RDK(AF, BF, CK, rA, rB)                          \
  do {                                                   \
    AF[0] = *(const half8*)((rA) + aro + (CK));          \
    AF[1] = *(const half8*)((rA) + 2048 + aro + (CK));   \
    AF[2] = *(const half8*)((rA) + 4096 + aro + (CK));   \
    AF[3] = *(const half8*)((rA) + 6144 + aro + (CK));   \
    BF[0] = *(const half8*)((rB) + aro + (CK));          \
    BF[1] = *(const half8*)((rB) + 2048 + aro + (CK));   \
  } while (0)

  // 8 independent 32x32x16 MFMAs (one kstep, whole 128x64 wave tile)
#define MFMA8(AF, BF)                                                       \
  do {                                                                     \
    PRIO1;                                                                 \
    acc[0][0] = __builtin_amdgcn_mfma_f32_32x32x16_f16(AF[0], BF[0], acc[0][0], 0, 0, 0); \
    acc[0][1] = __builtin_amdgcn_mfma_f32_32x32x16_f16(AF[0], BF[1], acc[0][1], 0, 0, 0); \
    acc[1][0] = __builtin_amdgcn_mfma_f32_32x32x16_f16(AF[1], BF[0], acc[1][0], 0, 0, 0); \
    acc[1][1] = __builtin_amdgcn_mfma_f32_32x32x16_f16(AF[1], BF[1], acc[1][1], 0, 0, 0); \
    acc[2][0] = __builtin_amdgcn_mfma_f32_32x32x16_f16(AF[2], BF[0], acc[2][0], 0, 0, 0); \
    acc[2][1] = __builtin_amdgcn_mfma_f32_32x32x16_f16(AF[2], BF[1], acc[2][1], 0, 0, 0); \
    acc[3][0] = __builtin_amdgcn_mfma_f32_32x32x16_f16(AF[3], BF[0], acc[3][0], 0, 0, 0); \
    acc[3][1] = __builtin_amdgcn_mfma_f32_32x32x16_f16(AF[3], BF[1], acc[3][1], 0, 0, 0); \
    PRIO0;                                                                 \
  } while (0)

  // One K-tile, one barrier. Reads for kstep k+1 issue before MFMA cluster k
  // (separate frag sets -> no WAR): LDS drains under MFMA pipe occupancy.
#define TILE32(BUF, T, S)                                   \
  do {                                                      \
    const _Float16* rA = lds + (BUF)*32768 + ha * 8192;     \
    const _Float16* rB = lds + (BUF)*32768 + 16384 + hboff; \
    RDK(afA, bfA, ck0, rA, rB);                             \
    if (S) {                                                \
      STAGE_A(0, (BUF) ^ 1, (T) + 1);                       \
      STAGE_A(1, (BUF) ^ 1, (T) + 1);                       \
      STAGE_B(0, (BUF) ^ 1, (T) + 1);                       \
      STAGE_B(1, (BUF) ^ 1, (T) + 1);                       \
    }                                                       \
    RDK(afB, bfB, ck1, rA, rB);                             \
    LG(6);                                                  \
    MFMA8(afA, bfA);                                        \
    RDK(afA, bfA, ck2, rA, rB);                             \
    LG(6);                                                  \
    MFMA8(afB, bfB);                                        \
    RDK(afB, bfB, ck3, rA, rB);                             \
    LG(6);                                                  \
    MFMA8(afA, bfA);                                        \
    LG(0);                                                  \
    MFMA8(afB, bfB);                                        \
    VMC(0);                                                 \
    BAR;                                                    \
  } while (0)

  // prologue: stage tile 0 into buf0; publish.
  STAGE_A(0, 0, 0);
  STAGE_A(1, 0, 0);
  STAGE_B(0, 0, 0);
  STAGE_B(1, 0, 0);
  VMC(0);
  BAR;

  for (int t2 = 0; t2 < NT - 2; t2 += 2) {
    TILE32(0, t2, 1);
    TILE32(1, t2 + 1, 1);
  }
  TILE32(0, NT - 2, 1);
  TILE32(1, NT - 1, 0);

  // epilogue: C/D col = lane&31 (n), row = (reg&3)+8*(reg>>2)+4*kh (m)
  const size_t rowbase = (size_t)by * 256 + ha * 128 + 4 * kh;
  const int colbase = bx * 256 + (w & 3) * 64 + l31;
#pragma unroll
  for (int mt = 0; mt < 4; ++mt) {
#pragma unroll
    for (int nt = 0; nt < 2; ++nt) {
#pragma unroll
      for (int i = 0; i < 16; ++i) {
        const size_t row = rowbase + mt * 32 + (i & 3) + 8 * (i >> 2);
        out[row * N_DIM + colbase + nt * 32] = acc[mt][nt][i];
      }
    }
  }
}

extern "C" void kernel_launch(void* const* d_in, const int* in_sizes, int n_in,
                              void* d_out, int out_size, void* d_ws, size_t ws_size,
                              hipStream_t stream) {
  const float* x      = (const float*)d_in[0];
  const float* lora_A = (const float*)d_in[1];
  const float* lora_B = (const float*)d_in[2];
  const float* absmax = (const float*)d_in[3];
  const int*   codes  = (const int*)d_in[4];
  float* out = (float*)d_out;

  _Float16* Xh = (_Float16*)d_ws;                 // 8192*4096 f16 = 64 MiB
  _Float16* Wc = Xh + (size_t)M_DIM * K_DIM;      // 4096*4096 f16 = 32 MiB

  hipLaunchKernelGGL(prep_x, dim3((M_DIM * K_DIM) / (8 * 256)), dim3(256), 0, stream,
                     (const float4*)x, (half8*)Xh);
  hipLaunchKernelGGL(prep_w, dim3((N_DIM / 128) * (K_DIM / 128)), dim3(256), 0, stream,
                     lora_A, lora_B, absmax, codes, Wc);
  hipLaunchKernelGGL(gemm, dim3((M_DIM / 256) * (N_DIM / 256)), dim3(512), 0, stream,
                     Xh, Wc, out);
}